// Round 4
// baseline (204.787 us; speedup 1.0000x reference)
//
#include <hip/hip_runtime.h>

#define NIMG 8
#define KCH 21
#define HIN 128
#define WIN 128
#define PD 4096      // 64*64 downsampled pixels
#define TP 64
#define TQ 64
#define NTILE (PD / TP)   // 64
// staging slot counts (float4): B-tile 21*64/4 = 336, F-tile 5*64/4 = 80
#define SLOTS_B 336
#define SLOTS_ALL 416

// ---------------- prep: downsample + features ----------------
// A[n][k][p] = avg2x2(logS) * roi_nearest ; B same for log1S
// F[n][c][p], c=0..4: r/15, g/15, b/15, x/50, y/50
__global__ __launch_bounds__(256)
void prep_kernel(const float* __restrict__ images,
                 const float* __restrict__ logS,
                 const float* __restrict__ log1S,
                 const float* __restrict__ rois,
                 float* __restrict__ A, float* __restrict__ B,
                 float* __restrict__ F)
{
    int idx = blockIdx.x * 256 + threadIdx.x;
    if (idx >= NIMG * KCH * PD) return;
    int p  = idx & (PD - 1);
    int nk = idx >> 12;            // PD = 2^12
    int k  = nk % KCH;
    int n  = nk / KCH;
    int i = p >> 6, j = p & 63;
    int base = (2 * i) * WIN + 2 * j;

    const float* ls = logS  + (size_t)nk * (HIN * WIN);
    const float* l1 = log1S + (size_t)nk * (HIN * WIN);
    float av = 0.25f * (ls[base] + ls[base + 1] + ls[base + WIN] + ls[base + WIN + 1]);
    float bv = 0.25f * (l1[base] + l1[base + 1] + l1[base + WIN] + l1[base + WIN + 1]);
    float roi = rois[(size_t)n * (HIN * WIN) + base];
    A[idx] = av * roi;
    B[idx] = bv * roi;

    if (k == 0) {
        const float* im = images + (size_t)n * 3 * (HIN * WIN);
        float* f = F + (size_t)n * 5 * PD;
        f[0 * PD + p] = im[base]                 * (1.0f / 15.0f);
        f[1 * PD + p] = im[HIN * WIN + base]     * (1.0f / 15.0f);
        f[2 * PD + p] = im[2 * HIN * WIN + base] * (1.0f / 15.0f);
        f[3 * PD + p] = (float)j * (1.0f / 50.0f);   // x
        f[4 * PD + p] = (float)i * (1.0f / 50.0f);   // y
    }
}

// ---------------- main: persistent p-tile, sweep q-tiles ----------------
// block = (p-tile, image); holds A-fragment + p-features in registers,
// loops over all q-tiles with reg-prefetched LDS staging of B/Fq.
__global__ __launch_bounds__(256)
void crf_kernel(const float* __restrict__ A, const float* __restrict__ B,
                const float* __restrict__ F, float* __restrict__ partials)
{
    __shared__ float sAp[KCH][TP];
    __shared__ float sFp[5][TP];
    __shared__ float sB[KCH][TQ];
    __shared__ float sFq[5][TQ];
    __shared__ float sred[4];

    const int n  = blockIdx.y;
    const int p0 = blockIdx.x * TP;
    const int tid = threadIdx.x;

    const float* An = A + (size_t)n * KCH * PD;
    const float* Bn = B + (size_t)n * KCH * PD;
    const float* Fn = F + (size_t)n * 5 * PD;

    // ---- stage p-side once (A-tile + Fp-tile) ----
    for (int s = tid; s < SLOTS_ALL; s += 256) {
        if (s < SLOTS_B) {
            int k = s >> 4, pp = (s & 15) << 2;
            *reinterpret_cast<float4*>(&sAp[k][pp]) =
                *reinterpret_cast<const float4*>(&An[k * PD + p0 + pp]);
        } else {
            int c = (s - SLOTS_B) >> 4, pp = ((s - SLOTS_B) & 15) << 2;
            *reinterpret_cast<float4*>(&sFp[c][pp]) =
                *reinterpret_cast<const float4*>(&Fn[c * PD + p0 + pp]);
        }
    }
    __syncthreads();

    const int tx = tid & 15, ty = tid >> 4;
    const int pi = ty << 2, qj = tx << 2;

    // ---- persistent registers: A-fragment (21x4) + p-features (5x4) ----
    float aF[KCH][4];
#pragma unroll
    for (int k = 0; k < KCH; ++k) {
        float4 av = *reinterpret_cast<const float4*>(&sAp[k][pi]);
        aF[k][0] = av.x; aF[k][1] = av.y; aF[k][2] = av.z; aF[k][3] = av.w;
    }
    float fp[5][4];
#pragma unroll
    for (int c = 0; c < 5; ++c) {
        float4 v4 = *reinterpret_cast<const float4*>(&sFp[c][pi]);
        fp[c][0] = v4.x; fp[c][1] = v4.y; fp[c][2] = v4.z; fp[c][3] = v4.w;
    }

    // staging slot mapping for this thread: slots {tid, tid+256}
    const int s0 = tid;                       // always < SLOTS_B
    const int k0 = s0 >> 4, pp0 = (s0 & 15) << 2;
    const int s1 = tid + 256;                 // valid if < SLOTS_ALL
    const bool s1v = (s1 < SLOTS_ALL);
    const bool s1b = (s1 < SLOTS_B);
    const int k1 = s1 >> 4, pp1 = (s1 & 15) << 2;
    const int c1 = (s1 - SLOTS_B) >> 4, pf1 = ((s1 - SLOTS_B) & 15) << 2;

    // ---- prefetch q-tile 0 into registers ----
    float4 pre0, pre1;
    pre0 = *reinterpret_cast<const float4*>(&Bn[k0 * PD + pp0]);
    if (s1v) {
        pre1 = s1b ? *reinterpret_cast<const float4*>(&Bn[k1 * PD + pp1])
                   : *reinterpret_cast<const float4*>(&Fn[c1 * PD + pf1]);
    }

    float partial = 0.0f;

    for (int qt = 0; qt < NTILE; ++qt) {
        const int q0 = qt * TQ;
        __syncthreads();   // prior-iteration LDS reads complete before overwrite
        // write prefetched regs -> LDS
        *reinterpret_cast<float4*>(&sB[k0][pp0]) = pre0;
        if (s1v) {
            if (s1b) *reinterpret_cast<float4*>(&sB[k1][pp1]) = pre1;
            else     *reinterpret_cast<float4*>(&sFq[c1][pf1]) = pre1;
        }
        // issue next-tile global loads early (latency hides under compute)
        if (qt + 1 < NTILE) {
            const int qn = q0 + TQ;
            pre0 = *reinterpret_cast<const float4*>(&Bn[k0 * PD + qn + pp0]);
            if (s1v) {
                pre1 = s1b ? *reinterpret_cast<const float4*>(&Bn[k1 * PD + qn + pp1])
                           : *reinterpret_cast<const float4*>(&Fn[c1 * PD + qn + pf1]);
            }
        }
        __syncthreads();

        // ---- K-dot: 21 x (1 ds_read_b128 + 16 FMA) ----
        float acc[4][4] = {};
#pragma unroll
        for (int k = 0; k < KCH; ++k) {
            float4 bv = *reinterpret_cast<const float4*>(&sB[k][qj]);
            float b0[4] = {bv.x, bv.y, bv.z, bv.w};
#pragma unroll
            for (int u = 0; u < 4; ++u)
#pragma unroll
                for (int v = 0; v < 4; ++v)
                    acc[u][v] = fmaf(aF[k][u], b0[v], acc[u][v]);
        }

        // ---- epilogue: bilateral weight x acc ----
        float fq[5][4];
#pragma unroll
        for (int c = 0; c < 5; ++c) {
            float4 v4 = *reinterpret_cast<const float4*>(&sFq[c][qj]);
            fq[c][0] = v4.x; fq[c][1] = v4.y; fq[c][2] = v4.z; fq[c][3] = v4.w;
        }
#pragma unroll
        for (int u = 0; u < 4; ++u)
#pragma unroll
            for (int v = 0; v < 4; ++v) {
                float d2 = 0.0f;
#pragma unroll
                for (int c = 0; c < 5; ++c) {
                    float d = fp[c][u] - fq[c][v];
                    d2 = fmaf(d, d, d2);
                }
                partial += __expf(-0.5f * d2) * acc[u][v];
            }
    }

    // ---- block reduction ----
#pragma unroll
    for (int off = 32; off > 0; off >>= 1)
        partial += __shfl_down(partial, off, 64);
    const int wave = tid >> 6, lane = tid & 63;
    if (lane == 0) sred[wave] = partial;
    __syncthreads();
    if (tid == 0) {
        partials[blockIdx.y * gridDim.x + blockIdx.x] =
            sred[0] + sred[1] + sred[2] + sred[3];
    }
}

// ---------------- final reduce ----------------
__global__ __launch_bounds__(256)
void reduce_kernel(const float* __restrict__ partials, float* __restrict__ out, int count)
{
    __shared__ float s[256];
    float sum = 0.0f;
    for (int i = threadIdx.x; i < count; i += 256) sum += partials[i];
    s[threadIdx.x] = sum;
    __syncthreads();
    for (int st = 128; st > 0; st >>= 1) {
        if (threadIdx.x < st) s[threadIdx.x] += s[threadIdx.x + st];
        __syncthreads();
    }
    if (threadIdx.x == 0) out[0] = s[0] * (1e-9f / 8.0f);  // WEIGHT * sum / N
}

extern "C" void kernel_launch(void* const* d_in, const int* in_sizes, int n_in,
                              void* d_out, int out_size, void* d_ws, size_t ws_size,
                              hipStream_t stream)
{
    const float* images = (const float*)d_in[0];
    const float* logS   = (const float*)d_in[1];
    const float* log1S  = (const float*)d_in[2];
    const float* rois   = (const float*)d_in[3];
    float* out = (float*)d_out;

    float* A        = (float*)d_ws;                 // N*K*P floats
    float* B        = A + NIMG * KCH * PD;          // N*K*P
    float* F        = B + NIMG * KCH * PD;          // N*5*P
    float* partials = F + NIMG * 5 * PD;            // N*NTILE = 512

    int prep_total = NIMG * KCH * PD;
    prep_kernel<<<(prep_total + 255) / 256, 256, 0, stream>>>(
        images, logS, log1S, rois, A, B, F);

    dim3 grid(NTILE, NIMG);
    crf_kernel<<<grid, 256, 0, stream>>>(A, B, F, partials);

    reduce_kernel<<<1, 256, 0, stream>>>(partials, out, NIMG * NTILE);
}

// Round 5
// 148.454 us; speedup vs baseline: 1.3795x; 1.3795x over previous
//
#include <hip/hip_runtime.h>

#define NIMG 8
#define KCH 21
#define HW2 16384       // 128*128 input pixels
#define PD 4096         // 64*64 downsampled
#define NT 256          // 16-wide tiles per image (4096/16)
#define LOG2E 1.4426950408889634f

typedef __attribute__((ext_vector_type(8))) short short8;   // 8 bf16 = 4 VGPR
typedef __attribute__((ext_vector_type(4))) float f32x4;

__device__ __forceinline__ unsigned short bf16rne(float x) {
    unsigned u = __float_as_uint(x);
    unsigned r = (u + 0x7FFFu + ((u >> 16) & 1u)) >> 16;
    return (unsigned short)r;
}
__device__ __forceinline__ float bf2f(unsigned short b) {
    return __uint_as_float(((unsigned)b) << 16);
}

// ---------- prep_ab: M-operands in MFMA fragment order ----------
// out flat idx t = [n][rt][g][m][e]; slot s=g*8+e is channel k (k>=21 -> 0),
// column/row p = rt*16+m. Value = bilinear-avg(logS or log1S)*roi, bf16.
__global__ __launch_bounds__(256)
void prep_ab(const float* __restrict__ logS, const float* __restrict__ log1S,
             const float* __restrict__ rois,
             unsigned short* __restrict__ AopM, unsigned short* __restrict__ BopM)
{
    unsigned t = blockIdx.x * 256 + threadIdx.x;   // 0 .. 2^20-1
    int e  = t & 7;
    int m  = (t >> 3) & 15;
    int g  = (t >> 7) & 3;
    int rt = (t >> 9) & 255;
    int n  = t >> 17;
    int k  = g * 8 + e;
    int p  = rt * 16 + m;
    int i = p >> 6, j = p & 63;
    int base = (i << 8) + (j << 1);                // (2i)*128 + 2j

    unsigned short va = 0, vb = 0;
    if (k < KCH) {
        float roi = rois[n * HW2 + base];
        const float* ls = logS  + (size_t)(n * KCH + k) * HW2;
        const float* l1 = log1S + (size_t)(n * KCH + k) * HW2;
        float a = 0.25f * (ls[base] + ls[base+1] + ls[base+128] + ls[base+129]) * roi;
        float b = 0.25f * (l1[base] + l1[base+1] + l1[base+128] + l1[base+129]) * roi;
        va = bf16rne(a);
        vb = bf16rne(b);
    }
    AopM[t] = va;
    BopM[t] = vb;
}

// ---------- prep_feat: Gram operands (split-bf16) + fp32 half-norms ----------
// GA slots: [hi(5) | hi(5) | lo(5) | lo(5) | 0...]
// GB slots: [hi(5) | lo(5) | hi(5) | lo(5) | 0...]
// sum_s GA_s*GB_s = (hi+lo)_p . (hi+lo)_q  exactly (fp32 accum).
__global__ __launch_bounds__(64)
void prep_feat(const float* __restrict__ images,
               unsigned short* __restrict__ GA, unsigned short* __restrict__ GB,
               float* __restrict__ Hh)
{
    int t = blockIdx.x * 64 + threadIdx.x;         // 0..32767
    int n = t >> 12, p = t & 4095;
    int i = p >> 6, j = p & 63;
    int base = (i << 8) + (j << 1);
    const float* img = images + (size_t)n * 3 * HW2;

    float f[5];
    f[0] = img[base]          * (1.0f / 15.0f);
    f[1] = img[HW2 + base]    * (1.0f / 15.0f);
    f[2] = img[2*HW2 + base]  * (1.0f / 15.0f);
    f[3] = (float)j * (1.0f / 50.0f);
    f[4] = (float)i * (1.0f / 50.0f);

    unsigned short hi[5], lo[5];
    float h = 0.0f;
#pragma unroll
    for (int c = 0; c < 5; ++c) {
        hi[c] = bf16rne(f[c]);
        float hf = bf2f(hi[c]);
        lo[c] = bf16rne(f[c] - hf);
        float fh = hf + bf2f(lo[c]);
        h = fmaf(fh, fh, h);
    }
    Hh[t] = 0.5f * h;

    int rt = p >> 4, m = p & 15;
    unsigned short* ga = GA + (size_t)(n * NT + rt) * 512 + m * 8;
    unsigned short* gb = GB + (size_t)(n * NT + rt) * 512 + m * 8;

    unsigned short av[32], bv[32];
#pragma unroll
    for (int s = 0; s < 32; ++s) {
        unsigned short a = 0, b = 0;
        if      (s < 5)  { a = hi[s];      b = hi[s];      }
        else if (s < 10) { a = hi[s - 5];  b = lo[s - 5];  }
        else if (s < 15) { a = lo[s - 10]; b = hi[s - 10]; }
        else if (s < 20) { a = lo[s - 15]; b = lo[s - 15]; }
        av[s] = a; bv[s] = b;
    }
#pragma unroll
    for (int g = 0; g < 4; ++g)
#pragma unroll
        for (int e2 = 0; e2 < 4; ++e2) {
            int s = g * 8 + e2 * 2;
            ushort2 pa; pa.x = av[s]; pa.y = av[s + 1];
            ushort2 pb; pb.x = bv[s]; pb.y = bv[s + 1];
            *reinterpret_cast<ushort2*>(ga + g * 128 + e2 * 2) = pa;
            *reinterpret_cast<ushort2*>(gb + g * 128 + e2 * 2) = pb;
        }
}

// ---------- crf: per-wave (rowtile, q-segment), MFMA dots, no LDS ----------
__global__ __launch_bounds__(256)
void crf_kernel(const unsigned short* __restrict__ AopM,
                const unsigned short* __restrict__ BopM,
                const unsigned short* __restrict__ GA,
                const unsigned short* __restrict__ GB,
                const float* __restrict__ Hh,
                float* __restrict__ partials)
{
    const int tid = threadIdx.x;
    const int l = tid & 63, w = tid >> 6;
    const int unit = blockIdx.x * 4 + w;       // 0..16383
    const int n = unit >> 11;
    const int rem = unit & 2047;
    const int rt = rem >> 3, seg = rem & 7;

    const short8 aM = *reinterpret_cast<const short8*>(AopM + (size_t)(n * NT + rt) * 512 + l * 8);
    const short8 aG = *reinterpret_cast<const short8*>(GA   + (size_t)(n * NT + rt) * 512 + l * 8);

    const float* hb = Hh + n * PD;
    float hpL[4];
    const int pr = rt * 16 + ((l >> 4) << 2);
#pragma unroll
    for (int r = 0; r < 4; ++r) hpL[r] = hb[pr + r] * LOG2E;

    const int ct0 = seg * 32;
    const unsigned short* bMp = BopM + (size_t)(n * NT + ct0) * 512 + l * 8;
    const unsigned short* bGp = GB   + (size_t)(n * NT + ct0) * 512 + l * 8;
    const float* hqp = hb + ct0 * 16 + (l & 15);

    float partial = 0.0f;
    const f32x4 zero = {0.0f, 0.0f, 0.0f, 0.0f};

    short8 bM0 = *reinterpret_cast<const short8*>(bMp);
    short8 bG0 = *reinterpret_cast<const short8*>(bGp);
    float  hq0 = hqp[0];

#pragma unroll 2
    for (int tt = 0; tt < 32; tt += 2) {
        // prefetch tile tt+1
        short8 bM1 = *reinterpret_cast<const short8*>(bMp + (tt + 1) * 512);
        short8 bG1 = *reinterpret_cast<const short8*>(bGp + (tt + 1) * 512);
        float  hq1 = hqp[(tt + 1) * 16];
        {
            f32x4 mm = __builtin_amdgcn_mfma_f32_16x16x32_bf16(aM, bM0, zero, 0, 0, 0);
            f32x4 gg = __builtin_amdgcn_mfma_f32_16x16x32_bf16(aG, bG0, zero, 0, 0, 0);
            float hqL = hq0 * LOG2E;
#pragma unroll
            for (int r = 0; r < 4; ++r) {
                float e2 = fmaf(gg[r], LOG2E, -(hpL[r] + hqL));
                partial = fmaf(exp2f(e2), mm[r], partial);
            }
        }
        if (tt + 2 < 32) {   // prefetch tile tt+2
            bM0 = *reinterpret_cast<const short8*>(bMp + (tt + 2) * 512);
            bG0 = *reinterpret_cast<const short8*>(bGp + (tt + 2) * 512);
            hq0 = hqp[(tt + 2) * 16];
        }
        {
            f32x4 mm = __builtin_amdgcn_mfma_f32_16x16x32_bf16(aM, bM1, zero, 0, 0, 0);
            f32x4 gg = __builtin_amdgcn_mfma_f32_16x16x32_bf16(aG, bG1, zero, 0, 0, 0);
            float hqL = hq1 * LOG2E;
#pragma unroll
            for (int r = 0; r < 4; ++r) {
                float e2 = fmaf(gg[r], LOG2E, -(hpL[r] + hqL));
                partial = fmaf(exp2f(e2), mm[r], partial);
            }
        }
    }

#pragma unroll
    for (int off = 32; off; off >>= 1)
        partial += __shfl_down(partial, off, 64);
    if (l == 0) partials[unit] = partial;
}

// ---------- final reduce ----------
__global__ __launch_bounds__(256)
void reduce_kernel(const float* __restrict__ partials, float* __restrict__ out, int count)
{
    __shared__ float s[256];
    float sum = 0.0f;
    for (int i = threadIdx.x; i < count; i += 256) sum += partials[i];
    s[threadIdx.x] = sum;
    __syncthreads();
    for (int st = 128; st > 0; st >>= 1) {
        if (threadIdx.x < st) s[threadIdx.x] += s[threadIdx.x + st];
        __syncthreads();
    }
    if (threadIdx.x == 0) out[0] = s[0] * (1e-9f / 8.0f);  // WEIGHT * sum / N
}

extern "C" void kernel_launch(void* const* d_in, const int* in_sizes, int n_in,
                              void* d_out, int out_size, void* d_ws, size_t ws_size,
                              hipStream_t stream)
{
    const float* images = (const float*)d_in[0];
    const float* logS   = (const float*)d_in[1];
    const float* log1S  = (const float*)d_in[2];
    const float* rois   = (const float*)d_in[3];
    float* out = (float*)d_out;

    unsigned short* AopM = (unsigned short*)d_ws;      // 2^20 u16 = 2MB
    unsigned short* BopM = AopM + (1u << 20);          // 2MB
    unsigned short* GA   = BopM + (1u << 20);          // 2MB
    unsigned short* GB   = GA   + (1u << 20);          // 2MB
    float* Hh            = (float*)(GB + (1u << 20));  // 32768 f32
    float* partials      = Hh + NIMG * PD;             // 16384 f32

    prep_ab<<<4096, 256, 0, stream>>>(logS, log1S, rois, AopM, BopM);
    prep_feat<<<512, 64, 0, stream>>>(images, GA, GB, Hh);
    crf_kernel<<<4096, 256, 0, stream>>>(AopM, BopM, GA, GB, Hh, partials);
    reduce_kernel<<<1, 256, 0, stream>>>(partials, out, NIMG * NT * 8);
}

// Round 7
// 117.645 us; speedup vs baseline: 1.7407x; 1.2619x over previous
//
#include <hip/hip_runtime.h>

#define NIMG 8
#define KCH 21
#define HW2 16384       // 128*128 input pixels
#define PD 4096         // 64*64 downsampled
#define NT 256          // 16-wide tiles per image (4096/16)
#define RT 4            // rowtiles per wave
#define SQRT_LOG2E 1.2011224087864498f

typedef __attribute__((ext_vector_type(8))) short short8;   // 8 bf16 = 4 VGPR
typedef __attribute__((ext_vector_type(4))) float f32x4;

__device__ __forceinline__ unsigned short bf16rne(float x) {
    unsigned u = __float_as_uint(x);
    unsigned r = (u + 0x7FFFu + ((u >> 16) & 1u)) >> 16;
    return (unsigned short)r;
}
__device__ __forceinline__ float bf2f(unsigned short b) {
    return __uint_as_float(((unsigned)b) << 16);
}

// ---------- prep_ab: M-operands, p-fastest mapping (coalesced reads) ----------
// u = [nk][p]; writes slot (g=k>>3, m=p&15, e=k&7) of tile rt=p>>4.
// Pad slots (k>=21) are zeroed by the memset in kernel_launch.
__global__ __launch_bounds__(256)
void prep_ab(const float* __restrict__ logS, const float* __restrict__ log1S,
             const float* __restrict__ rois,
             unsigned short* __restrict__ AopM, unsigned short* __restrict__ BopM)
{
    unsigned u = blockIdx.x * 256 + threadIdx.x;   // 0 .. 688127
    int p  = u & 4095;
    int nk = u >> 12;              // 0..167
    int n  = nk / KCH;
    int k  = nk - n * KCH;
    int i = p >> 6, j = p & 63;
    int base = (i << 8) + (j << 1);

    float roi = rois[n * HW2 + base];
    const float* ls = logS  + (size_t)nk * HW2;
    const float* l1 = log1S + (size_t)nk * HW2;
    float a = 0.25f * (ls[base] + ls[base+1] + ls[base+128] + ls[base+129]) * roi;
    float b = 0.25f * (l1[base] + l1[base+1] + l1[base+128] + l1[base+129]) * roi;

    size_t t = (size_t)((n * NT + (p >> 4)) * 4 + (k >> 3)) * 128 + (p & 15) * 8 + (k & 7);
    AopM[t] = bf16rne(a);
    BopM[t] = bf16rne(b);
}

// ---------- prep_feat: scaled Gram operands (split-bf16) + log2 half-norms ----
// f_hat = f * sqrt(log2 e); Hh = 0.5*|f_hat_repr|^2  (log2 units).
// GA slots: [hi(5)|hi(5)|lo(5)|lo(5)|0..]; GB: [hi|lo|hi|lo|0..]
__global__ __launch_bounds__(256)
void prep_feat(const float* __restrict__ images,
               unsigned short* __restrict__ GA, unsigned short* __restrict__ GB,
               float* __restrict__ Hh)
{
    int t = blockIdx.x * 256 + threadIdx.x;        // 0..32767
    int n = t >> 12, p = t & 4095;
    int i = p >> 6, j = p & 63;
    int base = (i << 8) + (j << 1);
    const float* img = images + (size_t)n * 3 * HW2;

    float f[5];
    f[0] = img[base]          * (SQRT_LOG2E / 15.0f);
    f[1] = img[HW2 + base]    * (SQRT_LOG2E / 15.0f);
    f[2] = img[2*HW2 + base]  * (SQRT_LOG2E / 15.0f);
    f[3] = (float)j * (SQRT_LOG2E / 50.0f);
    f[4] = (float)i * (SQRT_LOG2E / 50.0f);

    unsigned short hi[5], lo[5];
    float h = 0.0f;
#pragma unroll
    for (int c = 0; c < 5; ++c) {
        hi[c] = bf16rne(f[c]);
        float hf = bf2f(hi[c]);
        lo[c] = bf16rne(f[c] - hf);
        float fh = hf + bf2f(lo[c]);
        h = fmaf(fh, fh, h);
    }
    Hh[t] = 0.5f * h;

    int rt = p >> 4, m = p & 15;
    unsigned short* ga = GA + (size_t)(n * NT + rt) * 512 + m * 8;
    unsigned short* gb = GB + (size_t)(n * NT + rt) * 512 + m * 8;

    unsigned short av[32], bv[32];
#pragma unroll
    for (int s = 0; s < 32; ++s) {
        unsigned short a = 0, b = 0;
        if      (s < 5)  { a = hi[s];      b = hi[s];      }
        else if (s < 10) { a = hi[s - 5];  b = lo[s - 5];  }
        else if (s < 15) { a = lo[s - 10]; b = hi[s - 10]; }
        else if (s < 20) { a = lo[s - 15]; b = lo[s - 15]; }
        av[s] = a; bv[s] = b;
    }
#pragma unroll
    for (int g = 0; g < 4; ++g)
#pragma unroll
        for (int e2 = 0; e2 < 4; ++e2) {
            int s = g * 8 + e2 * 2;
            ushort2 pa; pa.x = av[s]; pa.y = av[s + 1];
            ushort2 pb; pb.x = bv[s]; pb.y = bv[s + 1];
            *reinterpret_cast<ushort2*>(ga + g * 128 + e2 * 2) = pa;
            *reinterpret_cast<ushort2*>(gb + g * 128 + e2 * 2) = pb;
        }
}

// ---------- crf: per-wave (4 rowtiles, q-segment); SGPR bases; raw exp2 ------
__global__ __launch_bounds__(256)
void crf_kernel(const unsigned short* __restrict__ AopM,
                const unsigned short* __restrict__ BopM,
                const unsigned short* __restrict__ GA,
                const unsigned short* __restrict__ GB,
                const float* __restrict__ Hh,
                float* __restrict__ partials)
{
    const int tid = threadIdx.x;
    const int l = tid & 63;
    const int w = __builtin_amdgcn_readfirstlane(tid >> 6);  // SGPR wave id
    const int unit = blockIdx.x * 4 + w;       // 0..4095
    const int n = unit >> 9;
    const int rem = unit & 511;
    const int rt0 = (rem >> 3) << 2;           // 4 rowtiles per wave
    const int seg = rem & 7;

    const int lf  = l * 8;                     // ushort offset in 512-elem tile
    const int lq  = l & 15;
    const int lr4 = (l >> 4) << 2;

    short8 aM[RT], aG[RT];
    float hp[RT][4];
    const float* hb = Hh + n * PD;
#pragma unroll
    for (int i = 0; i < RT; ++i) {
        const size_t tb = (size_t)(n * NT + rt0 + i) * 512;
        aM[i] = *reinterpret_cast<const short8*>(AopM + tb + lf);
        aG[i] = *reinterpret_cast<const short8*>(GA   + tb + lf);
        float4 h4 = *reinterpret_cast<const float4*>(hb + (rt0 + i) * 16 + lr4);
        hp[i][0] = h4.x; hp[i][1] = h4.y; hp[i][2] = h4.z; hp[i][3] = h4.w;
    }

    const int ct0 = seg * 32;
    const unsigned short* bMb = BopM + (size_t)(n * NT + ct0) * 512;  // uniform
    const unsigned short* bGb = GB   + (size_t)(n * NT + ct0) * 512;  // uniform
    const float* hqb = hb + ct0 * 16;                                 // uniform

    const f32x4 zero = {0.0f, 0.0f, 0.0f, 0.0f};
    float acc[RT] = {0.0f, 0.0f, 0.0f, 0.0f};

    short8 bm = *reinterpret_cast<const short8*>(bMb + lf);
    short8 bg = *reinterpret_cast<const short8*>(bGb + lf);
    float  hq = hqb[lq];

#pragma unroll 4
    for (int tt = 0; tt < 32; ++tt) {
        const int nx = (tt + 1 < 32) ? tt + 1 : 31;   // clamped prefetch
        short8 bm_n = *reinterpret_cast<const short8*>(bMb + nx * 512 + lf);
        short8 bg_n = *reinterpret_cast<const short8*>(bGb + nx * 512 + lf);
        float  hq_n = hqb[nx * 16 + lq];

#pragma unroll
        for (int i = 0; i < RT; ++i) {
            f32x4 mm = __builtin_amdgcn_mfma_f32_16x16x32_bf16(aM[i], bm, zero, 0, 0, 0);
            f32x4 gg = __builtin_amdgcn_mfma_f32_16x16x32_bf16(aG[i], bg, zero, 0, 0, 0);
#pragma unroll
            for (int r = 0; r < 4; ++r) {
                float e2 = gg[r] - (hp[i][r] + hq);   // log2(W), <= ~0
                float wgt;
                asm("v_exp_f32 %0, %1" : "=v"(wgt) : "v"(e2));  // raw exp2, FTZ ok
                acc[i] = fmaf(wgt, mm[r], acc[i]);
            }
        }
        bm = bm_n; bg = bg_n; hq = hq_n;
    }

    float partial = (acc[0] + acc[1]) + (acc[2] + acc[3]);
#pragma unroll
    for (int off = 32; off; off >>= 1)
        partial += __shfl_down(partial, off, 64);

    __shared__ float sred[4];
    if (l == 0) sred[w] = partial;
    __syncthreads();
    if (tid == 0)
        partials[blockIdx.x] = (sred[0] + sred[1]) + (sred[2] + sred[3]);
}

// ---------- final reduce ----------
__global__ __launch_bounds__(256)
void reduce_kernel(const float* __restrict__ partials, float* __restrict__ out, int count)
{
    __shared__ float s[256];
    float sum = 0.0f;
    for (int i = threadIdx.x; i < count; i += 256) sum += partials[i];
    s[threadIdx.x] = sum;
    __syncthreads();
    for (int st = 128; st > 0; st >>= 1) {
        if (threadIdx.x < st) s[threadIdx.x] += s[threadIdx.x + st];
        __syncthreads();
    }
    if (threadIdx.x == 0) out[0] = s[0] * (1e-9f / 8.0f);  // WEIGHT * sum / N
}

extern "C" void kernel_launch(void* const* d_in, const int* in_sizes, int n_in,
                              void* d_out, int out_size, void* d_ws, size_t ws_size,
                              hipStream_t stream)
{
    const float* images = (const float*)d_in[0];
    const float* logS   = (const float*)d_in[1];
    const float* log1S  = (const float*)d_in[2];
    const float* rois   = (const float*)d_in[3];
    float* out = (float*)d_out;

    unsigned short* AopM = (unsigned short*)d_ws;      // 2^20 u16 = 2MB
    unsigned short* BopM = AopM + (1u << 20);          // 2MB (contiguous with AopM)
    unsigned short* GA   = BopM + (1u << 20);          // 2MB
    unsigned short* GB   = GA   + (1u << 20);          // 2MB
    float* Hh            = (float*)(GB + (1u << 20));  // 32768 f32
    float* partials      = Hh + NIMG * PD;             // 1024 f32

    // zero pad slots (k>=21) of AopM+BopM (ws is poisoned 0xAA before each call)
    hipMemsetAsync(AopM, 0, (size_t)(1u << 21) * sizeof(unsigned short), stream);

    prep_ab<<<2688, 256, 0, stream>>>(logS, log1S, rois, AopM, BopM);
    prep_feat<<<128, 256, 0, stream>>>(images, GA, GB, Hh);
    crf_kernel<<<1024, 256, 0, stream>>>(AopM, BopM, GA, GB, Hh, partials);
    reduce_kernel<<<1, 256, 0, stream>>>(partials, out, 1024);
}

// Round 8
// 109.801 us; speedup vs baseline: 1.8651x; 1.0714x over previous
//
#include <hip/hip_runtime.h>

#define NIMG 8
#define KCH 21
#define HW2 16384       // 128*128 input pixels
#define PD 4096         // 64*64 downsampled
#define NT 256          // 16-wide tiles per image
#define RT 4            // rowtiles per wave
#define SQRT_LOG2E 1.2011224087864498f

typedef __attribute__((ext_vector_type(8))) short short8;   // 8 bf16 = 4 VGPR
typedef __attribute__((ext_vector_type(4))) float f32x4;

__device__ __forceinline__ unsigned short bf16rne(float x) {
    unsigned u = __float_as_uint(x);
    unsigned r = (u + 0x7FFFu + ((u >> 16) & 1u)) >> 16;
    return (unsigned short)r;
}
__device__ __forceinline__ float bf2f(unsigned short b) {
    return __uint_as_float(((unsigned)b) << 16);
}

// ---------------- fused prep ----------------
// blocks [0,2048): AB path. t=(n*32+k)*2048+h, 2 pixels p0=2h,p0+1 per thread.
//   float4 loads (coalesced); k in [21,32) writes zeros (pad slots).
// blocks [2048,2176): feat path. Gram operands with norm-offset slots:
//   GA slots: [hi(5)|hi(5)|lo(5)|lo(5)|nh_hi|nh_lo|1|1|0..]
//   GB slots: [hi(5)|lo(5)|hi(5)|lo(5)|1|1|nh_hi|nh_lo|0..]
//   => Gram MFMA output = f^p.f^q - hp - hq = log2(W_pq) directly.
__global__ __launch_bounds__(256)
void prep_kernel(const float* __restrict__ images,
                 const float* __restrict__ logS, const float* __restrict__ log1S,
                 const float* __restrict__ rois,
                 unsigned short* __restrict__ AopM, unsigned short* __restrict__ BopM,
                 unsigned short* __restrict__ GA, unsigned short* __restrict__ GB)
{
    const int bid = blockIdx.x;
    if (bid < 2048) {
        unsigned t = bid * 256 + threadIdx.x;   // 0..524287
        int h = t & 2047;
        int k = (t >> 11) & 31;
        int n = t >> 16;
        int p0 = h << 1;                        // even pixel
        size_t o = (size_t)((n * NT + (p0 >> 4)) * 4 + (k >> 3)) * 128
                 + (p0 & 15) * 8 + (k & 7);
        unsigned short a0 = 0, a1 = 0, b0 = 0, b1 = 0;
        if (k < KCH) {
            int i = p0 >> 6, j0 = p0 & 63;
            int base = (i << 8) + (j0 << 1);    // 16B-aligned (j0 even)
            int nk = n * KCH + k;
            const float* ls = logS  + (size_t)nk * HW2;
            const float* l1 = log1S + (size_t)nk * HW2;
            float4 lsa = *reinterpret_cast<const float4*>(ls + base);
            float4 lsb = *reinterpret_cast<const float4*>(ls + base + 128);
            float4 l1a = *reinterpret_cast<const float4*>(l1 + base);
            float4 l1b = *reinterpret_cast<const float4*>(l1 + base + 128);
            float4 rr  = *reinterpret_cast<const float4*>(rois + (size_t)n * HW2 + base);
            a0 = bf16rne(0.25f * (lsa.x + lsa.y + lsb.x + lsb.y) * rr.x);
            a1 = bf16rne(0.25f * (lsa.z + lsa.w + lsb.z + lsb.w) * rr.z);
            b0 = bf16rne(0.25f * (l1a.x + l1a.y + l1b.x + l1b.y) * rr.x);
            b1 = bf16rne(0.25f * (l1a.z + l1a.w + l1b.z + l1b.w) * rr.z);
        }
        AopM[o] = a0; AopM[o + 8] = a1;
        BopM[o] = b0; BopM[o + 8] = b1;
    } else {
        int t = (bid - 2048) * 256 + threadIdx.x;  // 0..32767
        int n = t >> 12, p = t & 4095;
        int i = p >> 6, j = p & 63;
        int base = (i << 8) + (j << 1);
        const float* img = images + (size_t)n * 3 * HW2;

        float f[5];
        f[0] = img[base]           * (SQRT_LOG2E / 15.0f);
        f[1] = img[HW2 + base]     * (SQRT_LOG2E / 15.0f);
        f[2] = img[2 * HW2 + base] * (SQRT_LOG2E / 15.0f);
        f[3] = (float)j * (SQRT_LOG2E / 50.0f);
        f[4] = (float)i * (SQRT_LOG2E / 50.0f);

        unsigned short hi[5], lo[5];
        float hsum = 0.0f;
#pragma unroll
        for (int c = 0; c < 5; ++c) {
            hi[c] = bf16rne(f[c]);
            float hf = bf2f(hi[c]);
            lo[c] = bf16rne(f[c] - hf);
            float fh = hf + bf2f(lo[c]);
            hsum = fmaf(fh, fh, hsum);
        }
        float nh = -0.5f * hsum;                 // -hp in log2 units
        unsigned short nhh = bf16rne(nh);
        unsigned short nhl = bf16rne(nh - bf2f(nhh));
        const unsigned short one = 0x3F80;       // bf16 1.0

        unsigned short av[32], bv[32];
#pragma unroll
        for (int s = 0; s < 32; ++s) { av[s] = 0; bv[s] = 0; }
#pragma unroll
        for (int c = 0; c < 5; ++c) {
            av[c]      = hi[c]; bv[c]      = hi[c];
            av[c + 5]  = hi[c]; bv[c + 5]  = lo[c];
            av[c + 10] = lo[c]; bv[c + 10] = hi[c];
            av[c + 15] = lo[c]; bv[c + 15] = lo[c];
        }
        av[20] = nhh; bv[20] = one;
        av[21] = nhl; bv[21] = one;
        av[22] = one; bv[22] = nhh;
        av[23] = one; bv[23] = nhl;

        int rt = p >> 4, m = p & 15;
        unsigned short* ga = GA + (size_t)(n * NT + rt) * 512 + m * 8;
        unsigned short* gb = GB + (size_t)(n * NT + rt) * 512 + m * 8;
#pragma unroll
        for (int g = 0; g < 4; ++g)
#pragma unroll
            for (int e2 = 0; e2 < 4; ++e2) {
                int s = g * 8 + e2 * 2;
                ushort2 pa; pa.x = av[s]; pa.y = av[s + 1];
                ushort2 pb; pb.x = bv[s]; pb.y = bv[s + 1];
                *reinterpret_cast<ushort2*>(ga + g * 128 + e2 * 2) = pa;
                *reinterpret_cast<ushort2*>(gb + g * 128 + e2 * 2) = pb;
            }
    }
}

// ---------- crf: per-wave (4 rowtiles, q-segment); Gram MFMA = log2W ----------
__global__ __launch_bounds__(256)
void crf_kernel(const unsigned short* __restrict__ AopM,
                const unsigned short* __restrict__ BopM,
                const unsigned short* __restrict__ GA,
                const unsigned short* __restrict__ GB,
                float* __restrict__ partials)
{
    const int tid = threadIdx.x;
    const int l = tid & 63;
    const int w = __builtin_amdgcn_readfirstlane(tid >> 6);
    const int unit = blockIdx.x * 4 + w;       // 0..4095
    const int n = unit >> 9;
    const int rem = unit & 511;
    const int rt0 = (rem >> 3) << 2;
    const int seg = rem & 7;
    const int lf = l * 8;

    short8 aM[RT], aG[RT];
#pragma unroll
    for (int i = 0; i < RT; ++i) {
        const size_t tb = (size_t)(n * NT + rt0 + i) * 512;
        aM[i] = *reinterpret_cast<const short8*>(AopM + tb + lf);
        aG[i] = *reinterpret_cast<const short8*>(GA   + tb + lf);
    }

    const int ct0 = seg * 32;
    const unsigned short* bMb = BopM + (size_t)(n * NT + ct0) * 512;  // uniform
    const unsigned short* bGb = GB   + (size_t)(n * NT + ct0) * 512;  // uniform

    const f32x4 zero = {0.0f, 0.0f, 0.0f, 0.0f};
    float acc[RT] = {0.0f, 0.0f, 0.0f, 0.0f};

    short8 bm = *reinterpret_cast<const short8*>(bMb + lf);
    short8 bg = *reinterpret_cast<const short8*>(bGb + lf);

#pragma unroll 4
    for (int tt = 0; tt < 32; ++tt) {
        const int nx = (tt + 1 < 32) ? tt + 1 : 31;
        short8 bm_n = *reinterpret_cast<const short8*>(bMb + nx * 512 + lf);
        short8 bg_n = *reinterpret_cast<const short8*>(bGb + nx * 512 + lf);

#pragma unroll
        for (int i = 0; i < RT; ++i) {
            f32x4 mm = __builtin_amdgcn_mfma_f32_16x16x32_bf16(aM[i], bm, zero, 0, 0, 0);
            f32x4 gg = __builtin_amdgcn_mfma_f32_16x16x32_bf16(aG[i], bg, zero, 0, 0, 0);
#pragma unroll
            for (int r = 0; r < 4; ++r) {
                float wgt;
                asm("v_exp_f32 %0, %1" : "=v"(wgt) : "v"(gg[r]));  // W = 2^(log2W)
                acc[i] = fmaf(wgt, mm[r], acc[i]);
            }
        }
        bm = bm_n; bg = bg_n;
    }

    float partial = (acc[0] + acc[1]) + (acc[2] + acc[3]);
#pragma unroll
    for (int off = 32; off; off >>= 1)
        partial += __shfl_down(partial, off, 64);

    __shared__ float sred[4];
    if (l == 0) sred[w] = partial;
    __syncthreads();
    if (tid == 0)
        partials[blockIdx.x] = (sred[0] + sred[1]) + (sred[2] + sred[3]);
}

// ---------------- final reduce ----------------
__global__ __launch_bounds__(256)
void reduce_kernel(const float* __restrict__ partials, float* __restrict__ out, int count)
{
    __shared__ float s[256];
    float sum = 0.0f;
    for (int i = threadIdx.x; i < count; i += 256) sum += partials[i];
    s[threadIdx.x] = sum;
    __syncthreads();
    for (int st = 128; st > 0; st >>= 1) {
        if (threadIdx.x < st) s[threadIdx.x] += s[threadIdx.x + st];
        __syncthreads();
    }
    if (threadIdx.x == 0) out[0] = s[0] * (1e-9f / 8.0f);  // WEIGHT * sum / N
}

extern "C" void kernel_launch(void* const* d_in, const int* in_sizes, int n_in,
                              void* d_out, int out_size, void* d_ws, size_t ws_size,
                              hipStream_t stream)
{
    const float* images = (const float*)d_in[0];
    const float* logS   = (const float*)d_in[1];
    const float* log1S  = (const float*)d_in[2];
    const float* rois   = (const float*)d_in[3];
    float* out = (float*)d_out;

    unsigned short* AopM = (unsigned short*)d_ws;      // 2MB
    unsigned short* BopM = AopM + (1u << 20);          // 2MB
    unsigned short* GA   = BopM + (1u << 20);          // 2MB
    unsigned short* GB   = GA   + (1u << 20);          // 2MB
    float* partials      = (float*)(GB + (1u << 20));  // 1024 f32

    prep_kernel<<<2176, 256, 0, stream>>>(images, logS, log1S, rois,
                                          AopM, BopM, GA, GB);
    crf_kernel<<<1024, 256, 0, stream>>>(AopM, BopM, GA, GB, partials);
    reduce_kernel<<<1, 256, 0, stream>>>(partials, out, 1024);
}

// Round 9
// 109.301 us; speedup vs baseline: 1.8736x; 1.0046x over previous
//
#include <hip/hip_runtime.h>

#define NIMG 8
#define KCH 21
#define HW2 16384       // 128*128 input pixels
#define PD 4096         // 64*64 downsampled
#define NT 256          // 16-wide tiles per image
#define RT 8            // rowtiles per wave
#define NSEG 16         // q-segments (16 tiles each)
#define SQRT_LOG2E 1.2011224087864498f

typedef __attribute__((ext_vector_type(8))) short short8;   // 8 bf16 = 4 VGPR
typedef __attribute__((ext_vector_type(4))) float f32x4;

__device__ __forceinline__ unsigned short bf16rne(float x) {
    unsigned u = __float_as_uint(x);
    unsigned r = (u + 0x7FFFu + ((u >> 16) & 1u)) >> 16;
    return (unsigned short)r;
}
__device__ __forceinline__ float bf2f(unsigned short b) {
    return __uint_as_float(((unsigned)b) << 16);
}

// ---------------- fused prep ----------------
// blocks [0,2048): AB path, 2 pixels/thread, float4 coalesced loads.
// blocks [2048,2176): feat path, Gram operands with norm-offset slots:
//   GA: [hi(5)|hi(5)|lo(5)|lo(5)|nh_hi|nh_lo|1|1|0..]
//   GB: [hi(5)|lo(5)|hi(5)|lo(5)|1|1|nh_hi|nh_lo|0..]
//   => Gram MFMA output = f^p.f^q - hp - hq = log2(W_pq) directly.
// Block 0 thread 0 also zeroes out[0] for crf's atomicAdd.
__global__ __launch_bounds__(256)
void prep_kernel(const float* __restrict__ images,
                 const float* __restrict__ logS, const float* __restrict__ log1S,
                 const float* __restrict__ rois,
                 unsigned short* __restrict__ AopM, unsigned short* __restrict__ BopM,
                 unsigned short* __restrict__ GA, unsigned short* __restrict__ GB,
                 float* __restrict__ out)
{
    const int bid = blockIdx.x;
    if (bid == 0 && threadIdx.x == 0) out[0] = 0.0f;
    if (bid < 2048) {
        unsigned t = bid * 256 + threadIdx.x;   // 0..524287
        int h = t & 2047;
        int k = (t >> 11) & 31;
        int n = t >> 16;
        int p0 = h << 1;                        // even pixel
        size_t o = (size_t)((n * NT + (p0 >> 4)) * 4 + (k >> 3)) * 128
                 + (p0 & 15) * 8 + (k & 7);
        unsigned short a0 = 0, a1 = 0, b0 = 0, b1 = 0;
        if (k < KCH) {
            int i = p0 >> 6, j0 = p0 & 63;
            int base = (i << 8) + (j0 << 1);    // 16B-aligned (j0 even)
            int nk = n * KCH + k;
            const float* ls = logS  + (size_t)nk * HW2;
            const float* l1 = log1S + (size_t)nk * HW2;
            float4 lsa = *reinterpret_cast<const float4*>(ls + base);
            float4 lsb = *reinterpret_cast<const float4*>(ls + base + 128);
            float4 l1a = *reinterpret_cast<const float4*>(l1 + base);
            float4 l1b = *reinterpret_cast<const float4*>(l1 + base + 128);
            float4 rr  = *reinterpret_cast<const float4*>(rois + (size_t)n * HW2 + base);
            a0 = bf16rne(0.25f * (lsa.x + lsa.y + lsb.x + lsb.y) * rr.x);
            a1 = bf16rne(0.25f * (lsa.z + lsa.w + lsb.z + lsb.w) * rr.z);
            b0 = bf16rne(0.25f * (l1a.x + l1a.y + l1b.x + l1b.y) * rr.x);
            b1 = bf16rne(0.25f * (l1a.z + l1a.w + l1b.z + l1b.w) * rr.z);
        }
        AopM[o] = a0; AopM[o + 8] = a1;
        BopM[o] = b0; BopM[o + 8] = b1;
    } else {
        int t = (bid - 2048) * 256 + threadIdx.x;  // 0..32767
        int n = t >> 12, p = t & 4095;
        int i = p >> 6, j = p & 63;
        int base = (i << 8) + (j << 1);
        const float* img = images + (size_t)n * 3 * HW2;

        float f[5];
        f[0] = img[base]           * (SQRT_LOG2E / 15.0f);
        f[1] = img[HW2 + base]     * (SQRT_LOG2E / 15.0f);
        f[2] = img[2 * HW2 + base] * (SQRT_LOG2E / 15.0f);
        f[3] = (float)j * (SQRT_LOG2E / 50.0f);
        f[4] = (float)i * (SQRT_LOG2E / 50.0f);

        unsigned short hi[5], lo[5];
        float hsum = 0.0f;
#pragma unroll
        for (int c = 0; c < 5; ++c) {
            hi[c] = bf16rne(f[c]);
            float hf = bf2f(hi[c]);
            lo[c] = bf16rne(f[c] - hf);
            float fh = hf + bf2f(lo[c]);
            hsum = fmaf(fh, fh, hsum);
        }
        float nh = -0.5f * hsum;                 // -hp in log2 units
        unsigned short nhh = bf16rne(nh);
        unsigned short nhl = bf16rne(nh - bf2f(nhh));
        const unsigned short one = 0x3F80;       // bf16 1.0

        unsigned short av[32], bv[32];
#pragma unroll
        for (int s = 0; s < 32; ++s) { av[s] = 0; bv[s] = 0; }
#pragma unroll
        for (int c = 0; c < 5; ++c) {
            av[c]      = hi[c]; bv[c]      = hi[c];
            av[c + 5]  = hi[c]; bv[c + 5]  = lo[c];
            av[c + 10] = lo[c]; bv[c + 10] = hi[c];
            av[c + 15] = lo[c]; bv[c + 15] = lo[c];
        }
        av[20] = nhh; bv[20] = one;
        av[21] = nhl; bv[21] = one;
        av[22] = one; bv[22] = nhh;
        av[23] = one; bv[23] = nhl;

        int rt = p >> 4, m = p & 15;
        unsigned short* ga = GA + (size_t)(n * NT + rt) * 512 + m * 8;
        unsigned short* gb = GB + (size_t)(n * NT + rt) * 512 + m * 8;
#pragma unroll
        for (int g = 0; g < 4; ++g)
#pragma unroll
            for (int e2 = 0; e2 < 4; ++e2) {
                int s = g * 8 + e2 * 2;
                ushort2 pa; pa.x = av[s]; pa.y = av[s + 1];
                ushort2 pb; pb.x = bv[s]; pb.y = bv[s + 1];
                *reinterpret_cast<ushort2*>(ga + g * 128 + e2 * 2) = pa;
                *reinterpret_cast<ushort2*>(gb + g * 128 + e2 * 2) = pb;
            }
    }
}

// ---- crf: per-wave (8 rowtiles, 16-tile q-segment); Gram MFMA = log2W ------
__global__ __launch_bounds__(256)
void crf_kernel(const unsigned short* __restrict__ AopM,
                const unsigned short* __restrict__ BopM,
                const unsigned short* __restrict__ GA,
                const unsigned short* __restrict__ GB,
                float* __restrict__ out)
{
    const int tid = threadIdx.x;
    const int l = tid & 63;
    const int w = __builtin_amdgcn_readfirstlane(tid >> 6);
    const int unit = blockIdx.x * 4 + w;       // 0..4095
    const int n = unit >> 9;                   // 512 units per image
    const int rem = unit & 511;
    const int rt0 = (rem >> 4) << 3;           // 8 rowtiles per wave
    const int seg = rem & 15;
    const int lf = l * 8;

    short8 aM[RT], aG[RT];
#pragma unroll
    for (int i = 0; i < RT; ++i) {
        const size_t tb = (size_t)(n * NT + rt0 + i) * 512;
        aM[i] = *reinterpret_cast<const short8*>(AopM + tb + lf);
        aG[i] = *reinterpret_cast<const short8*>(GA   + tb + lf);
    }

    const int ct0 = seg * 16;
    const unsigned short* bMb = BopM + (size_t)(n * NT + ct0) * 512;  // uniform
    const unsigned short* bGb = GB   + (size_t)(n * NT + ct0) * 512;  // uniform

    const f32x4 zero = {0.0f, 0.0f, 0.0f, 0.0f};
    float acc[RT] = {};

    short8 bm = *reinterpret_cast<const short8*>(bMb + lf);
    short8 bg = *reinterpret_cast<const short8*>(bGb + lf);

#pragma unroll 4
    for (int tt = 0; tt < 16; ++tt) {
        const int nx = (tt + 1 < 16) ? tt + 1 : 15;   // clamped prefetch
        short8 bm_n = *reinterpret_cast<const short8*>(bMb + nx * 512 + lf);
        short8 bg_n = *reinterpret_cast<const short8*>(bGb + nx * 512 + lf);

#pragma unroll
        for (int i = 0; i < RT; ++i) {
            f32x4 mm = __builtin_amdgcn_mfma_f32_16x16x32_bf16(aM[i], bm, zero, 0, 0, 0);
            f32x4 gg = __builtin_amdgcn_mfma_f32_16x16x32_bf16(aG[i], bg, zero, 0, 0, 0);
#pragma unroll
            for (int r = 0; r < 4; ++r) {
                float wgt;
                asm("v_exp_f32 %0, %1" : "=v"(wgt) : "v"(gg[r]));  // W = 2^(log2W)
                acc[i] = fmaf(wgt, mm[r], acc[i]);
            }
        }
        bm = bm_n; bg = bg_n;
    }

    float partial = ((acc[0] + acc[1]) + (acc[2] + acc[3]))
                  + ((acc[4] + acc[5]) + (acc[6] + acc[7]));
#pragma unroll
    for (int off = 32; off; off >>= 1)
        partial += __shfl_down(partial, off, 64);

    __shared__ float sred[4];
    if (l == 0) sred[w] = partial;
    __syncthreads();
    if (tid == 0) {
        float s = (sred[0] + sred[1]) + (sred[2] + sred[3]);
        atomicAdd(out, s * (1e-9f / 8.0f));    // WEIGHT * sum / N, pre-scaled
    }
}

extern "C" void kernel_launch(void* const* d_in, const int* in_sizes, int n_in,
                              void* d_out, int out_size, void* d_ws, size_t ws_size,
                              hipStream_t stream)
{
    const float* images = (const float*)d_in[0];
    const float* logS   = (const float*)d_in[1];
    const float* log1S  = (const float*)d_in[2];
    const float* rois   = (const float*)d_in[3];
    float* out = (float*)d_out;

    unsigned short* AopM = (unsigned short*)d_ws;      // 2MB
    unsigned short* BopM = AopM + (1u << 20);          // 2MB
    unsigned short* GA   = BopM + (1u << 20);          // 2MB
    unsigned short* GB   = GA   + (1u << 20);          // 2MB

    prep_kernel<<<2176, 256, 0, stream>>>(images, logS, log1S, rois,
                                          AopM, BopM, GA, GB, out);
    crf_kernel<<<1024, 256, 0, stream>>>(AopM, BopM, GA, GB, out);
}